// Round 10
// baseline (161.921 us; speedup 1.0000x reference)
//
#include <hip/hip_runtime.h>
#include <cstdint>
#include <cstddef>

#define B_DIM 8
#define U_DIM 1024
#define SD    1024                 // SIZE == D_ATT == 1024
#define M_DIM (B_DIM * U_DIM)      // 8192 rows; also B*D channel count
#define NC 32                      // scan chunks
#define CT 32                      // tokens per chunk (NC*CT == U_DIM)

typedef __attribute__((ext_vector_type(8))) short short8;
typedef __attribute__((ext_vector_type(4))) float f32x4;

typedef __attribute__((address_space(3))) void       lds_t;
typedef const __attribute__((address_space(1))) void glb_t;

__device__ __forceinline__ ushort f2bf(float f) {
    union { float f; uint32_t u; } c; c.f = f;
    uint32_t r = (c.u + 0x7FFFu + ((c.u >> 16) & 1u)) >> 16;   // RNE
    return (ushort)r;
}
__device__ __forceinline__ float bf2f(ushort h) {
    union { float f; uint32_t u; } c; c.u = ((uint32_t)h) << 16; return c.f;
}

// ---------------- prepass: W[K][N] f32 -> W^T[N][K] bf16, 4 matrices ----------------
__global__ __launch_bounds__(256)
void wtrans_kernel(const float* __restrict__ Wk, const float* __restrict__ Wv,
                   const float* __restrict__ Wr, const float* __restrict__ Wo,
                   ushort* __restrict__ WT)
{
    __shared__ float t[32][33];
    const float* W = (blockIdx.z == 0) ? Wk : (blockIdx.z == 1) ? Wv
                   : (blockIdx.z == 2) ? Wr : Wo;
    ushort* o = WT + (size_t)blockIdx.z * SD * SD;
    const int tx = threadIdx.x & 31, ty = threadIdx.x >> 5;
    const int k0 = blockIdx.y * 32, n0 = blockIdx.x * 32;
    #pragma unroll
    for (int i = 0; i < 4; ++i)
        t[ty + i * 8][tx] = W[(size_t)(k0 + ty + i * 8) * SD + n0 + tx];
    __syncthreads();
    #pragma unroll
    for (int i = 0; i < 4; ++i)
        o[(size_t)(n0 + ty + i * 8) * SD + k0 + tx] = f2bf(t[tx][ty + i * 8]);
}

// ---------------- prepass: A_j = sh + mix_j*(x - sh), bf16, all three in one pass ----
__global__ __launch_bounds__(256)
void mix3_kernel(const float* __restrict__ x,
                 const float* __restrict__ mk, const float* __restrict__ mv,
                 const float* __restrict__ mr,
                 ushort* __restrict__ Ak, ushort* __restrict__ Av,
                 ushort* __restrict__ Ar)
{
    const int idx = blockIdx.x * 256 + threadIdx.x;  // 2M groups of 4
    const int m = idx >> 8;
    const int s = (idx & 255) << 2;
    const float4 xv = *(const float4*)&x[(size_t)m * SD + s];
    float4 sh = make_float4(0.f, 0.f, 0.f, 0.f);
    if (m & (U_DIM - 1)) sh = *(const float4*)&x[(size_t)(m - 1) * SD + s];
    const float4 dx = make_float4(xv.x - sh.x, xv.y - sh.y, xv.z - sh.z, xv.w - sh.w);
    const size_t off = (size_t)m * SD + s;

    float4 mx;
    ushort4 o;
    mx = *(const float4*)&mk[s];
    o.x = f2bf(sh.x + mx.x * dx.x); o.y = f2bf(sh.y + mx.y * dx.y);
    o.z = f2bf(sh.z + mx.z * dx.z); o.w = f2bf(sh.w + mx.w * dx.w);
    *(ushort4*)&Ak[off] = o;
    mx = *(const float4*)&mv[s];
    o.x = f2bf(sh.x + mx.x * dx.x); o.y = f2bf(sh.y + mx.y * dx.y);
    o.z = f2bf(sh.z + mx.z * dx.z); o.w = f2bf(sh.w + mx.w * dx.w);
    *(ushort4*)&Av[off] = o;
    mx = *(const float4*)&mr[s];
    o.x = f2bf(sh.x + mx.x * dx.x); o.y = f2bf(sh.y + mx.y * dx.y);
    o.z = f2bf(sh.z + mx.z * dx.z); o.w = f2bf(sh.w + mx.w * dx.w);
    *(ushort4*)&Ar[off] = o;
}

// ---------------- single-projection mix (fallback path) ----------------
__global__ __launch_bounds__(256)
void mix_kernel(const float* __restrict__ x, const float* __restrict__ mix,
                ushort* __restrict__ outA)
{
    const int idx = blockIdx.x * 256 + threadIdx.x;
    const int m = idx >> 8;
    const int s = (idx & 255) << 2;
    const float4 xv = *(const float4*)&x[(size_t)m * SD + s];
    float4 sh = make_float4(0.f, 0.f, 0.f, 0.f);
    if (m & (U_DIM - 1)) sh = *(const float4*)&x[(size_t)(m - 1) * SD + s];
    const float4 mx = *(const float4*)&mix[s];
    ushort4 o;
    o.x = f2bf(sh.x + mx.x * (xv.x - sh.x));
    o.y = f2bf(sh.y + mx.y * (xv.y - sh.y));
    o.z = f2bf(sh.z + mx.z * (xv.z - sh.z));
    o.w = f2bf(sh.w + mx.w * (xv.w - sh.w));
    *(ushort4*)&outA[(size_t)m * SD + s] = o;
}

// ======== 128x64 bf16 MFMA GEMM — drain loop, 8-waves/SIMD residency ========
// C[M,N] = A[M,K] @ (BT[N,K])^T + bias   M=8192, K=1024
// FUSED==3: grid (64,48): z = by>>4 selects {k,v,r}; sigmoid at z==2; bf16 out
// FUSED==0/1: grid (64,16): bf16 out (1: +sigmoid)     FUSED==2: f32 out
// 256 threads = 4 waves (2M x 2N), wave tile 64x32 (4x2 16x16 frags -> acc = 32
// VGPR). __launch_bounds__(256,8) forces VGPR <= 64 -> 8 waves/SIMD -> 8 blocks/CU
// co-resident (vs 4 at the 64x64 tile's VGPR 72-88; m69 occupancy steps at 64).
// The drain loop is latency-bound per block (~23% MfmaUtil at 2.5 resident blocks,
// rounds 7-9); residency is the scaling axis -> double blocks, double overlap.
// LDS 12 KB single buffer: As[128][32] 8 KB + Bs[64][32] 4 KB, 64 B rows.
// 16B chunk q stored from source chunk q^((row>>1)&3) (0-conflict, rounds 3-9);
// fragment reads apply the same XOR.
template<int FUSED>
__global__ __launch_bounds__(256, 8)
void gemm64(const ushort* __restrict__ Abase, const ushort* __restrict__ WTbase,
            const float* __restrict__ b0, const float* __restrict__ b1,
            const float* __restrict__ b2, void* __restrict__ Cbase)
{
    __shared__ ushort As[128 * 32];   // 8 KB  [row][32k], 64 B rows
    __shared__ ushort Bs[64 * 32];    // 4 KB

    const int tid = threadIdx.x;
    const int wv = tid >> 6, ln = tid & 63;
    const int wm = (wv >> 1) * 64, wn = (wv & 1) * 32;

    const int m0 = blockIdx.x * 128;
    int nb = (int)blockIdx.y, z = 0;
    if (FUSED == 3) { z = nb >> 4; nb &= 15; }
    const int n0 = nb * 64;

    const ushort* A; const ushort* BT; const float* bias; void* Cout; int dosig;
    if (FUSED == 3) {
        A    = Abase + (size_t)z * ((size_t)M_DIM * SD);
        BT   = WTbase + (size_t)z * ((size_t)SD * SD);
        bias = (z == 0) ? b0 : (z == 1) ? b1 : b2;
        Cout = (void*)((ushort*)Cbase + (size_t)z * ((size_t)M_DIM * SD));
        dosig = (z == 2);
    } else {
        A = Abase; BT = WTbase; bias = b0; Cout = Cbase; dosig = (FUSED == 1);
    }

    // ---- staging maps (linear LDS dest = chunk*16B; inverse-swizzled global src) ----
    const int srow = tid >> 2;                                 // 0..63 (+64 for A rows)
    const int sq   = ((tid & 3) ^ ((srow >> 1) & 3)) << 3;     // elem offset in row
    const ushort* aS = A  + (size_t)(m0 + srow) * SD + sq;
    const ushort* bS = BT + (size_t)(n0 + srow) * SD + sq;     // B: 64 rows, 1 issue
    char* const laW = (char*)As + wv * 1024;                   // wave-uniform bases
    char* const lbW = (char*)Bs + wv * 1024;

    // ---- fragment-read maps (swizzled) ----
    const int lr  = ln & 15;
    const int lq  = ln >> 4;
    const int kof = (lq ^ ((lr >> 1) & 3)) << 4;               // byte offset of chunk
    const char* LAc = (const char*)As;
    const char* LBc = (const char*)Bs;
    const int aRd = wm * 64 + lr * 64 + kof;                   // rows 64.. at +4096
    const int bRd = wn * 64 + lr * 64 + kof;                   // rows 32.. at +2048

    f32x4 acc[4][2];
    #pragma unroll
    for (int i = 0; i < 4; ++i)
        #pragma unroll
        for (int j = 0; j < 2; ++j)
            acc[i][j] = (f32x4){0.f, 0.f, 0.f, 0.f};

    for (int k0 = 0; k0 < SD; k0 += 32) {
        // ---- stage tile (3 global_load_lds per thread-quarter; 12 KB total) ----
        __builtin_amdgcn_global_load_lds((glb_t*)(aS + k0),                   (lds_t*)laW,          16, 0, 0);
        __builtin_amdgcn_global_load_lds((glb_t*)(aS + (size_t)64 * SD + k0), (lds_t*)(laW + 4096), 16, 0, 0);
        __builtin_amdgcn_global_load_lds((glb_t*)(bS + k0),                   (lds_t*)lbW,          16, 0, 0);
        __syncthreads();   // compiler drains vmcnt(0) before s_barrier

        short8 af[4], bq[2];
        #pragma unroll
        for (int mt = 0; mt < 4; ++mt)
            af[mt] = *(const short8*)(LAc + mt * 1024 + aRd);
        #pragma unroll
        for (int nt = 0; nt < 2; ++nt)
            bq[nt] = *(const short8*)(LBc + nt * 1024 + bRd);
        #pragma unroll
        for (int mt = 0; mt < 4; ++mt)
            #pragma unroll
            for (int nt = 0; nt < 2; ++nt)
                acc[mt][nt] = __builtin_amdgcn_mfma_f32_16x16x32_bf16(
                    af[mt], bq[nt], acc[mt][nt], 0, 0, 0);
        __syncthreads();
    }

    // ---- epilogue: frag row = lq*4 + j, col = lr (m89-verified) ----
    const int cr = lq * 4;
    const int cc = lr;
    #pragma unroll
    for (int mt = 0; mt < 4; ++mt)
    #pragma unroll
    for (int nt = 0; nt < 2; ++nt) {
        const int gc = n0 + wn + nt * 16 + cc;
        const float bv = bias[gc];
        #pragma unroll
        for (int j = 0; j < 4; ++j) {
            const int gr = m0 + wm + mt * 16 + cr + j;
            float v = acc[mt][nt][j] + bv;
            if (FUSED == 1 || FUSED == 3) { if (dosig) v = 1.f / (1.f + __expf(-v)); }
            if (FUSED == 2)
                ((float*)Cout)[(size_t)gr * SD + gc] = v;
            else
                ((ushort*)Cout)[(size_t)gr * SD + gc] = f2bf(v);
        }
    }
}

// ---------------- scan pass 1: per-chunk local states from zero init ----------------
__global__ __launch_bounds__(256)
void scan_local(const ushort* __restrict__ kq, const ushort* __restrict__ vq,
                const float* __restrict__ td,
                float* __restrict__ sa, float* __restrict__ sb, float* __restrict__ sp)
{
    const int idx = blockIdx.x * 256 + threadIdx.x;   // 8192*NC
    const int ch = idx & (M_DIM - 1);
    const int c  = idx >> 13;
    const int b  = ch >> 10, d = ch & (SD - 1);
    const float w = -__expf(td[d]);
    size_t ptr = (size_t)b * U_DIM * SD + (size_t)(c * CT) * SD + d;

    float a = 0.f, bb = 0.f, p = -1e38f;
    for (int s = 0; s < CT; ++s) {
        const float kt = bf2f(kq[ptr]), vt = bf2f(vq[ptr]);
        const float q2 = fmaxf(p + w, kt);
        const float e1 = __expf(p + w - q2);
        const float e2 = __expf(kt - q2);
        a = e1 * a + e2 * vt; bb = e1 * bb + e2; p = q2;
        ptr += SD;
    }
    sa[idx] = a; sb[idx] = bb; sp[idx] = p;
}

// ---------------- scan pass 2: sequential prefix-combine over chunks ----------------
__global__ __launch_bounds__(256)
void scan_prefix(const float* __restrict__ td,
                 float* __restrict__ sa, float* __restrict__ sb, float* __restrict__ sp)
{
    const int ch = blockIdx.x * 256 + threadIdx.x;    // 8192
    const float wT = -__expf(td[ch & (SD - 1)]) * (float)CT;
    float ca = 0.f, cb = 0.f, cp = -1e38f;
    for (int c = 0; c < NC; ++c) {
        const int i = c * M_DIM + ch;
        const float la = sa[i], lb = sb[i], lp = sp[i];
        sa[i] = ca; sb[i] = cb; sp[i] = cp;
        const float pd = cp + wT;                      // decay carry across chunk
        const float q  = fmaxf(pd, lp);
        const float e1 = __expf(pd - q);
        const float e2 = __expf(lp - q);
        ca = e1 * ca + e2 * la; cb = e1 * cb + e2 * lb; cp = q;
    }
}

// ---------------- scan pass 3: outputs r*wkv (bf16) from incoming states ----------------
__global__ __launch_bounds__(256)
void scan_out(const ushort* __restrict__ kq, const ushort* __restrict__ vq,
              const ushort* __restrict__ rq,
              const float* __restrict__ td, const float* __restrict__ tfirst,
              const float* __restrict__ sa, const float* __restrict__ sb,
              const float* __restrict__ sp,
              ushort* __restrict__ rw)
{
    const int idx = blockIdx.x * 256 + threadIdx.x;
    const int ch = idx & (M_DIM - 1);
    const int c  = idx >> 13;
    const int b  = ch >> 10, d = ch & (SD - 1);
    const float w  = -__expf(td[d]);
    const float tf = tfirst[d];
    size_t ptr = (size_t)b * U_DIM * SD + (size_t)(c * CT) * SD + d;

    float a = sa[idx], bb = sb[idx], p = sp[idx];
    for (int s = 0; s < CT; ++s) {
        const float kt = bf2f(kq[ptr]), vt = bf2f(vq[ptr]), rt = bf2f(rq[ptr]);
        const float q  = fmaxf(p, tf + kt);
        const float e1 = __expf(p - q);
        const float e2 = __expf(tf + kt - q);
        const float ov = (e1 * a + e2 * vt) * __builtin_amdgcn_rcpf(e1 * bb + e2);
        const float q2  = fmaxf(p + w, kt);
        const float e1b = __expf(p + w - q2);
        const float e2b = __expf(kt - q2);
        a = e1b * a + e2b * vt; bb = e1b * bb + e2b; p = q2;
        rw[ptr] = f2bf(rt * ov);
        ptr += SD;
    }
}

extern "C" void kernel_launch(void* const* d_in, const int* in_sizes, int n_in,
                              void* d_out, int out_size, void* d_ws, size_t ws_size,
                              hipStream_t stream)
{
    (void)in_sizes; (void)n_in; (void)out_size;
    const float* x  = (const float*)d_in[0];
    const float* td = (const float*)d_in[1];
    const float* tf = (const float*)d_in[2];
    const float* mk = (const float*)d_in[3];
    const float* mv = (const float*)d_in[4];
    const float* mr = (const float*)d_in[5];
    const float* Wk = (const float*)d_in[6];
    const float* bk = (const float*)d_in[7];
    const float* Wv = (const float*)d_in[8];
    const float* bv = (const float*)d_in[9];
    const float* Wr = (const float*)d_in[10];
    const float* br = (const float*)d_in[11];
    const float* Wo = (const float*)d_in[12];
    const float* bo = (const float*)d_in[13];
    float* out = (float*)d_out;

    const size_t NE = (size_t)M_DIM * SD;   // 8M elements
    const size_t WS = (size_t)SD * SD;
    char* ws = (char*)d_ws;

    const dim3 gg1(64, 16, 1);
    const dim3 gg3(64, 48, 1);

    if (ws_size >= ((size_t)108 << 20)) {
        // fused layout: WT 0-8 | Ak 8-24 | Av 24-40 | Ar 40-56 | k 56-72 | v 72-88 |
        //               r 88-104 | states 104-107  (MB)
        ushort* WT  = (ushort*)ws;
        ushort* Ak  = (ushort*)(ws + ((size_t)8   << 20));
        ushort* kvr = (ushort*)(ws + ((size_t)56  << 20));
        float*  sa  = (float*)(ws + ((size_t)104 << 20));
        float*  sb  = (float*)(ws + ((size_t)105 << 20));
        float*  sp  = (float*)(ws + ((size_t)106 << 20));
        ushort* kbuf = kvr;
        ushort* vbuf = kvr + NE;
        ushort* rbuf = kvr + 2 * NE;
        ushort* rwkv = Ak;                  // A-buffers dead after proj GEMM

        wtrans_kernel<<<dim3(32, 32, 4), 256, 0, stream>>>(Wk, Wv, Wr, Wo, WT);
        mix3_kernel<<<8192, 256, 0, stream>>>(x, mk, mv, mr, Ak, Ak + NE, Ak + 2 * NE);
        gemm64<3><<<gg3, 256, 0, stream>>>(Ak, WT, bk, bv, br, kvr);

        scan_local <<<(M_DIM * NC) / 256, 256, 0, stream>>>(kbuf, vbuf, td, sa, sb, sp);
        scan_prefix<<<M_DIM / 256, 256, 0, stream>>>(td, sa, sb, sp);
        scan_out   <<<(M_DIM * NC) / 256, 256, 0, stream>>>(kbuf, vbuf, rbuf, td, tf,
                                                            sa, sb, sp, rwkv);

        gemm64<2><<<gg1, 256, 0, stream>>>(rwkv, WT + 3 * WS, bo, bo, bo, out);
    } else {
        // sequential layout (75 MB)
        ushort* WT   = (ushort*)ws;
        ushort* Abuf = (ushort*)(ws + ((size_t)8  << 20));
        ushort* kbuf = (ushort*)(ws + ((size_t)24 << 20));
        ushort* vbuf = (ushort*)(ws + ((size_t)40 << 20));
        ushort* rbuf = (ushort*)(ws + ((size_t)56 << 20));
        float*  sa   = (float*)(ws + ((size_t)72 << 20));
        float*  sb   = (float*)(ws + ((size_t)73 << 20));
        float*  sp   = (float*)(ws + ((size_t)74 << 20));
        ushort* rwkv = Abuf;

        wtrans_kernel<<<dim3(32, 32, 4), 256, 0, stream>>>(Wk, Wv, Wr, Wo, WT);
        mix_kernel<<<8192, 256, 0, stream>>>(x, mk, Abuf);
        gemm64<0><<<gg1, 256, 0, stream>>>(Abuf, WT, bk, bk, bk, kbuf);
        mix_kernel<<<8192, 256, 0, stream>>>(x, mv, Abuf);
        gemm64<0><<<gg1, 256, 0, stream>>>(Abuf, WT + WS, bv, bv, bv, vbuf);
        mix_kernel<<<8192, 256, 0, stream>>>(x, mr, Abuf);
        gemm64<1><<<gg1, 256, 0, stream>>>(Abuf, WT + 2 * WS, br, br, br, rbuf);

        scan_local <<<(M_DIM * NC) / 256, 256, 0, stream>>>(kbuf, vbuf, td, sa, sb, sp);
        scan_prefix<<<M_DIM / 256, 256, 0, stream>>>(td, sa, sb, sp);
        scan_out   <<<(M_DIM * NC) / 256, 256, 0, stream>>>(kbuf, vbuf, rbuf, td, tf,
                                                            sa, sb, sp, rwkv);

        gemm64<2><<<gg1, 256, 0, stream>>>(rwkv, WT + 3 * WS, bo, bo, bo, out);
    }
}

// Round 11
// 146.171 us; speedup vs baseline: 1.1077x; 1.1077x over previous
//
#include <hip/hip_runtime.h>
#include <cstdint>
#include <cstddef>

#define B_DIM 8
#define U_DIM 1024
#define SD    1024                 // SIZE == D_ATT == 1024
#define M_DIM (B_DIM * U_DIM)      // 8192 rows; also B*D channel count
#define NC 32                      // scan chunks
#define CT 32                      // tokens per chunk (NC*CT == U_DIM)

typedef __attribute__((ext_vector_type(8))) short short8;
typedef __attribute__((ext_vector_type(4))) float f32x4;

typedef __attribute__((address_space(3))) void       lds_t;
typedef const __attribute__((address_space(1))) void glb_t;

__device__ __forceinline__ ushort f2bf(float f) {
    union { float f; uint32_t u; } c; c.f = f;
    uint32_t r = (c.u + 0x7FFFu + ((c.u >> 16) & 1u)) >> 16;   // RNE
    return (ushort)r;
}
__device__ __forceinline__ float bf2f(ushort h) {
    union { float f; uint32_t u; } c; c.u = ((uint32_t)h) << 16; return c.f;
}

// ---------------- prepass: W[K][N] f32 -> W^T[N][K] bf16, 4 matrices ----------------
__global__ __launch_bounds__(256)
void wtrans_kernel(const float* __restrict__ Wk, const float* __restrict__ Wv,
                   const float* __restrict__ Wr, const float* __restrict__ Wo,
                   ushort* __restrict__ WT)
{
    __shared__ float t[32][33];
    const float* W = (blockIdx.z == 0) ? Wk : (blockIdx.z == 1) ? Wv
                   : (blockIdx.z == 2) ? Wr : Wo;
    ushort* o = WT + (size_t)blockIdx.z * SD * SD;
    const int tx = threadIdx.x & 31, ty = threadIdx.x >> 5;
    const int k0 = blockIdx.y * 32, n0 = blockIdx.x * 32;
    #pragma unroll
    for (int i = 0; i < 4; ++i)
        t[ty + i * 8][tx] = W[(size_t)(k0 + ty + i * 8) * SD + n0 + tx];
    __syncthreads();
    #pragma unroll
    for (int i = 0; i < 4; ++i)
        o[(size_t)(n0 + ty + i * 8) * SD + k0 + tx] = f2bf(t[tx][ty + i * 8]);
}

// ---------------- prepass: A_j = sh + mix_j*(x - sh), bf16, all three in one pass ----
__global__ __launch_bounds__(256)
void mix3_kernel(const float* __restrict__ x,
                 const float* __restrict__ mk, const float* __restrict__ mv,
                 const float* __restrict__ mr,
                 ushort* __restrict__ Ak, ushort* __restrict__ Av,
                 ushort* __restrict__ Ar)
{
    const int idx = blockIdx.x * 256 + threadIdx.x;  // 2M groups of 4
    const int m = idx >> 8;
    const int s = (idx & 255) << 2;
    const float4 xv = *(const float4*)&x[(size_t)m * SD + s];
    float4 sh = make_float4(0.f, 0.f, 0.f, 0.f);
    if (m & (U_DIM - 1)) sh = *(const float4*)&x[(size_t)(m - 1) * SD + s];
    const float4 dx = make_float4(xv.x - sh.x, xv.y - sh.y, xv.z - sh.z, xv.w - sh.w);
    const size_t off = (size_t)m * SD + s;

    float4 mx;
    ushort4 o;
    mx = *(const float4*)&mk[s];
    o.x = f2bf(sh.x + mx.x * dx.x); o.y = f2bf(sh.y + mx.y * dx.y);
    o.z = f2bf(sh.z + mx.z * dx.z); o.w = f2bf(sh.w + mx.w * dx.w);
    *(ushort4*)&Ak[off] = o;
    mx = *(const float4*)&mv[s];
    o.x = f2bf(sh.x + mx.x * dx.x); o.y = f2bf(sh.y + mx.y * dx.y);
    o.z = f2bf(sh.z + mx.z * dx.z); o.w = f2bf(sh.w + mx.w * dx.w);
    *(ushort4*)&Av[off] = o;
    mx = *(const float4*)&mr[s];
    o.x = f2bf(sh.x + mx.x * dx.x); o.y = f2bf(sh.y + mx.y * dx.y);
    o.z = f2bf(sh.z + mx.z * dx.z); o.w = f2bf(sh.w + mx.w * dx.w);
    *(ushort4*)&Ar[off] = o;
}

// ---------------- single-projection mix (fallback path) ----------------
__global__ __launch_bounds__(256)
void mix_kernel(const float* __restrict__ x, const float* __restrict__ mix,
                ushort* __restrict__ outA)
{
    const int idx = blockIdx.x * 256 + threadIdx.x;
    const int m = idx >> 8;
    const int s = (idx & 255) << 2;
    const float4 xv = *(const float4*)&x[(size_t)m * SD + s];
    float4 sh = make_float4(0.f, 0.f, 0.f, 0.f);
    if (m & (U_DIM - 1)) sh = *(const float4*)&x[(size_t)(m - 1) * SD + s];
    const float4 mx = *(const float4*)&mix[s];
    ushort4 o;
    o.x = f2bf(sh.x + mx.x * (xv.x - sh.x));
    o.y = f2bf(sh.y + mx.y * (xv.y - sh.y));
    o.z = f2bf(sh.z + mx.z * (xv.z - sh.z));
    o.w = f2bf(sh.w + mx.w * (xv.w - sh.w));
    *(ushort4*)&outA[(size_t)m * SD + s] = o;
}

// ======== 128x128 bf16 MFMA GEMM — counted-vmcnt 2-phase (T4), BK=32 ========
// C[M,N] = A[M,K] @ (BT[N,K])^T + bias   M=8192, K=1024
// FUSED==3: grid (64,24): z = by>>3 selects {k,v,r}; sigmoid at z==2; bf16 out
// FUSED==0/1: grid (64,8): bf16 out (1: +sigmoid)      FUSED==2: f32 out
// 256 threads = 4 waves (2M x 2N), wave tile 64x64 (4x4 16x16 frags).
// DOUBLE 16 KB buffers (32 KB LDS -> 5 blocks/CU; VGPR ~80). Per K-step:
//   STG(buf^1, t+1)                       // prefetch issued (4 gload_lds/wave)
//   s_waitcnt vmcnt(4)                    // tile t's 4 complete; t+1's stay IN FLIGHT
//   s_barrier                             // publish tile t (raw: no vmcnt drain!)
//   CMP(buf)                              // 8 ds_read_b128 + 16 MFMA
//   s_barrier                             // WAR: all reads of buf done before restage
// This is round 9's intent with the one bug fixed: __syncthreads drained the
// just-issued prefetch (vmcnt(0) = ALL outstanding); raw barrier + vmcnt(4) lets
// the prefetch cross the barrier, so exposed latency = max(0, lat - CMP).
// LDS 16B chunk q stored from source chunk q^((row>>1)&3) (0-conflict, rounds 3-10);
// fragment reads apply the same XOR.
template<int FUSED>
__global__ __launch_bounds__(256)
void gemm128(const ushort* __restrict__ Abase, const ushort* __restrict__ WTbase,
             const float* __restrict__ b0, const float* __restrict__ b1,
             const float* __restrict__ b2, void* __restrict__ Cbase)
{
    __shared__ ushort As[2 * 128 * 32];   // 2 x 8 KB  [buf][row][32k], 64 B rows
    __shared__ ushort Bs[2 * 128 * 32];   // 2 x 8 KB

    const int tid = threadIdx.x;
    const int wv = tid >> 6, ln = tid & 63;
    const int wm = (wv >> 1) * 64, wn = (wv & 1) * 64;

    const int m0 = blockIdx.x * 128;
    int nb = (int)blockIdx.y, z = 0;
    if (FUSED == 3) { z = nb >> 3; nb &= 7; }
    const int n0 = nb * 128;

    const ushort* A; const ushort* BT; const float* bias; void* Cout; int dosig;
    if (FUSED == 3) {
        A    = Abase + (size_t)z * ((size_t)M_DIM * SD);
        BT   = WTbase + (size_t)z * ((size_t)SD * SD);
        bias = (z == 0) ? b0 : (z == 1) ? b1 : b2;
        Cout = (void*)((ushort*)Cbase + (size_t)z * ((size_t)M_DIM * SD));
        dosig = (z == 2);
    } else {
        A = Abase; BT = WTbase; bias = b0; Cout = Cbase; dosig = (FUSED == 1);
    }

    // ---- staging maps (linear LDS dest = chunk*16B; inverse-swizzled global src) ----
    const int srow = tid >> 2;                                 // 0..63 (+64 2nd issue)
    const int sq   = ((tid & 3) ^ ((srow >> 1) & 3)) << 3;     // elem offset in row
    const ushort* aS = A  + (size_t)(m0 + srow) * SD + sq;
    const ushort* bS = BT + (size_t)(n0 + srow) * SD + sq;
    char* const laW = (char*)As + wv * 1024;                   // wave-uniform bases
    char* const lbW = (char*)Bs + wv * 1024;

    // ---- fragment-read maps (swizzled) ----
    const int lr  = ln & 15;
    const int lq  = ln >> 4;
    const int kof = (lq ^ ((lr >> 1) & 3)) << 4;               // byte offset of chunk
    const char* LAc = (const char*)As;
    const char* LBc = (const char*)Bs;
    const int aRd = wm * 64 + lr * 64 + kof;
    const int bRd = wn * 64 + lr * 64 + kof;

    f32x4 acc[4][4];
    #pragma unroll
    for (int i = 0; i < 4; ++i)
        #pragma unroll
        for (int j = 0; j < 4; ++j)
            acc[i][j] = (f32x4){0.f, 0.f, 0.f, 0.f};

#define STG(buf, kt)                                                                  \
    do { const int k0_ = (kt) * 32;                                                   \
        __builtin_amdgcn_global_load_lds((glb_t*)(aS + k0_),                          \
            (lds_t*)(laW + (buf) * 8192), 16, 0, 0);                                  \
        __builtin_amdgcn_global_load_lds((glb_t*)(aS + (size_t)64 * SD + k0_),        \
            (lds_t*)(laW + (buf) * 8192 + 4096), 16, 0, 0);                           \
        __builtin_amdgcn_global_load_lds((glb_t*)(bS + k0_),                          \
            (lds_t*)(lbW + (buf) * 8192), 16, 0, 0);                                  \
        __builtin_amdgcn_global_load_lds((glb_t*)(bS + (size_t)64 * SD + k0_),        \
            (lds_t*)(lbW + (buf) * 8192 + 4096), 16, 0, 0);                           \
    } while (0)

#define CMP(buf)                                                                      \
    do {                                                                              \
        short8 af[4], bq[4];                                                          \
        _Pragma("unroll")                                                             \
        for (int mt = 0; mt < 4; ++mt)                                                \
            af[mt] = *(const short8*)(LAc + (buf) * 8192 + mt * 1024 + aRd);          \
        _Pragma("unroll")                                                             \
        for (int nt = 0; nt < 4; ++nt)                                                \
            bq[nt] = *(const short8*)(LBc + (buf) * 8192 + nt * 1024 + bRd);          \
        _Pragma("unroll")                                                             \
        for (int mt = 0; mt < 4; ++mt)                                                \
            _Pragma("unroll")                                                         \
            for (int nt = 0; nt < 4; ++nt)                                            \
                acc[mt][nt] = __builtin_amdgcn_mfma_f32_16x16x32_bf16(                \
                    af[mt], bq[nt], acc[mt][nt], 0, 0, 0);                            \
    } while (0)

    // ---- prologue: stage tile 0 into buf0 (4 loads in flight) ----
    STG(0, 0);

    // ---- main loop: counted-vmcnt pipeline, prefetch survives the barrier ----
    #pragma unroll
    for (int t = 0; t < 32; ++t) {
        const int b  = t & 1;
        const int tn = (t + 1 < 32) ? t + 1 : 31;   // tail clamp: dead-buffer restage
        STG(b ^ 1, tn);                             // 8 outstanding after this
        asm volatile("s_waitcnt vmcnt(4)" ::: "memory");   // tile t ready; t+1 in flight
        __builtin_amdgcn_s_barrier();
        asm volatile("" ::: "memory");
        CMP(b);
        asm volatile("" ::: "memory");
        __builtin_amdgcn_s_barrier();               // WAR: reads of buf b retired
        asm volatile("" ::: "memory");
    }

#undef CMP
#undef STG

    // ---- epilogue: frag row = lq*4 + j, col = lr (m89-verified) ----
    const int cr = lq * 4;
    const int cc = lr;
    #pragma unroll
    for (int mt = 0; mt < 4; ++mt)
    #pragma unroll
    for (int nt = 0; nt < 4; ++nt) {
        const int gc = n0 + wn + nt * 16 + cc;
        const float bv = bias[gc];
        #pragma unroll
        for (int j = 0; j < 4; ++j) {
            const int gr = m0 + wm + mt * 16 + cr + j;
            float v = acc[mt][nt][j] + bv;
            if (FUSED == 1 || FUSED == 3) { if (dosig) v = 1.f / (1.f + __expf(-v)); }
            if (FUSED == 2)
                ((float*)Cout)[(size_t)gr * SD + gc] = v;
            else
                ((ushort*)Cout)[(size_t)gr * SD + gc] = f2bf(v);
        }
    }
}

// ---------------- scan pass 1: per-chunk local states from zero init ----------------
__global__ __launch_bounds__(256)
void scan_local(const ushort* __restrict__ kq, const ushort* __restrict__ vq,
                const float* __restrict__ td,
                float* __restrict__ sa, float* __restrict__ sb, float* __restrict__ sp)
{
    const int idx = blockIdx.x * 256 + threadIdx.x;   // 8192*NC
    const int ch = idx & (M_DIM - 1);
    const int c  = idx >> 13;
    const int b  = ch >> 10, d = ch & (SD - 1);
    const float w = -__expf(td[d]);
    size_t ptr = (size_t)b * U_DIM * SD + (size_t)(c * CT) * SD + d;

    float a = 0.f, bb = 0.f, p = -1e38f;
    for (int s = 0; s < CT; ++s) {
        const float kt = bf2f(kq[ptr]), vt = bf2f(vq[ptr]);
        const float q2 = fmaxf(p + w, kt);
        const float e1 = __expf(p + w - q2);
        const float e2 = __expf(kt - q2);
        a = e1 * a + e2 * vt; bb = e1 * bb + e2; p = q2;
        ptr += SD;
    }
    sa[idx] = a; sb[idx] = bb; sp[idx] = p;
}

// ---------------- scan pass 2: sequential prefix-combine over chunks ----------------
__global__ __launch_bounds__(256)
void scan_prefix(const float* __restrict__ td,
                 float* __restrict__ sa, float* __restrict__ sb, float* __restrict__ sp)
{
    const int ch = blockIdx.x * 256 + threadIdx.x;    // 8192
    const float wT = -__expf(td[ch & (SD - 1)]) * (float)CT;
    float ca = 0.f, cb = 0.f, cp = -1e38f;
    for (int c = 0; c < NC; ++c) {
        const int i = c * M_DIM + ch;
        const float la = sa[i], lb = sb[i], lp = sp[i];
        sa[i] = ca; sb[i] = cb; sp[i] = cp;
        const float pd = cp + wT;                      // decay carry across chunk
        const float q  = fmaxf(pd, lp);
        const float e1 = __expf(pd - q);
        const float e2 = __expf(lp - q);
        ca = e1 * ca + e2 * la; cb = e1 * cb + e2 * lb; cp = q;
    }
}

// ---------------- scan pass 3: outputs r*wkv (bf16) from incoming states ----------------
__global__ __launch_bounds__(256)
void scan_out(const ushort* __restrict__ kq, const ushort* __restrict__ vq,
              const ushort* __restrict__ rq,
              const float* __restrict__ td, const float* __restrict__ tfirst,
              const float* __restrict__ sa, const float* __restrict__ sb,
              const float* __restrict__ sp,
              ushort* __restrict__ rw)
{
    const int idx = blockIdx.x * 256 + threadIdx.x;
    const int ch = idx & (M_DIM - 1);
    const int c  = idx >> 13;
    const int b  = ch >> 10, d = ch & (SD - 1);
    const float w  = -__expf(td[d]);
    const float tf = tfirst[d];
    size_t ptr = (size_t)b * U_DIM * SD + (size_t)(c * CT) * SD + d;

    float a = sa[idx], bb = sb[idx], p = sp[idx];
    for (int s = 0; s < CT; ++s) {
        const float kt = bf2f(kq[ptr]), vt = bf2f(vq[ptr]), rt = bf2f(rq[ptr]);
        const float q  = fmaxf(p, tf + kt);
        const float e1 = __expf(p - q);
        const float e2 = __expf(tf + kt - q);
        const float ov = (e1 * a + e2 * vt) * __builtin_amdgcn_rcpf(e1 * bb + e2);
        const float q2  = fmaxf(p + w, kt);
        const float e1b = __expf(p + w - q2);
        const float e2b = __expf(kt - q2);
        a = e1b * a + e2b * vt; bb = e1b * bb + e2b; p = q2;
        rw[ptr] = f2bf(rt * ov);
        ptr += SD;
    }
}

extern "C" void kernel_launch(void* const* d_in, const int* in_sizes, int n_in,
                              void* d_out, int out_size, void* d_ws, size_t ws_size,
                              hipStream_t stream)
{
    (void)in_sizes; (void)n_in; (void)out_size;
    const float* x  = (const float*)d_in[0];
    const float* td = (const float*)d_in[1];
    const float* tf = (const float*)d_in[2];
    const float* mk = (const float*)d_in[3];
    const float* mv = (const float*)d_in[4];
    const float* mr = (const float*)d_in[5];
    const float* Wk = (const float*)d_in[6];
    const float* bk = (const float*)d_in[7];
    const float* Wv = (const float*)d_in[8];
    const float* bv = (const float*)d_in[9];
    const float* Wr = (const float*)d_in[10];
    const float* br = (const float*)d_in[11];
    const float* Wo = (const float*)d_in[12];
    const float* bo = (const float*)d_in[13];
    float* out = (float*)d_out;

    const size_t NE = (size_t)M_DIM * SD;   // 8M elements
    const size_t WS = (size_t)SD * SD;
    char* ws = (char*)d_ws;

    const dim3 gg1(64, 8, 1);
    const dim3 gg3(64, 24, 1);

    if (ws_size >= ((size_t)108 << 20)) {
        // fused layout: WT 0-8 | Ak 8-24 | Av 24-40 | Ar 40-56 | k 56-72 | v 72-88 |
        //               r 88-104 | states 104-107  (MB)
        ushort* WT  = (ushort*)ws;
        ushort* Ak  = (ushort*)(ws + ((size_t)8   << 20));
        ushort* kvr = (ushort*)(ws + ((size_t)56  << 20));
        float*  sa  = (float*)(ws + ((size_t)104 << 20));
        float*  sb  = (float*)(ws + ((size_t)105 << 20));
        float*  sp  = (float*)(ws + ((size_t)106 << 20));
        ushort* kbuf = kvr;
        ushort* vbuf = kvr + NE;
        ushort* rbuf = kvr + 2 * NE;
        ushort* rwkv = Ak;                  // A-buffers dead after proj GEMM

        wtrans_kernel<<<dim3(32, 32, 4), 256, 0, stream>>>(Wk, Wv, Wr, Wo, WT);
        mix3_kernel<<<8192, 256, 0, stream>>>(x, mk, mv, mr, Ak, Ak + NE, Ak + 2 * NE);
        gemm128<3><<<gg3, 256, 0, stream>>>(Ak, WT, bk, bv, br, kvr);

        scan_local <<<(M_DIM * NC) / 256, 256, 0, stream>>>(kbuf, vbuf, td, sa, sb, sp);
        scan_prefix<<<M_DIM / 256, 256, 0, stream>>>(td, sa, sb, sp);
        scan_out   <<<(M_DIM * NC) / 256, 256, 0, stream>>>(kbuf, vbuf, rbuf, td, tf,
                                                            sa, sb, sp, rwkv);

        gemm128<2><<<gg1, 256, 0, stream>>>(rwkv, WT + 3 * WS, bo, bo, bo, out);
    } else {
        // sequential layout (75 MB)
        ushort* WT   = (ushort*)ws;
        ushort* Abuf = (ushort*)(ws + ((size_t)8  << 20));
        ushort* kbuf = (ushort*)(ws + ((size_t)24 << 20));
        ushort* vbuf = (ushort*)(ws + ((size_t)40 << 20));
        ushort* rbuf = (ushort*)(ws + ((size_t)56 << 20));
        float*  sa   = (float*)(ws + ((size_t)72 << 20));
        float*  sb   = (float*)(ws + ((size_t)73 << 20));
        float*  sp   = (float*)(ws + ((size_t)74 << 20));
        ushort* rwkv = Abuf;

        wtrans_kernel<<<dim3(32, 32, 4), 256, 0, stream>>>(Wk, Wv, Wr, Wo, WT);
        mix_kernel<<<8192, 256, 0, stream>>>(x, mk, Abuf);
        gemm128<0><<<gg1, 256, 0, stream>>>(Abuf, WT, bk, bk, bk, kbuf);
        mix_kernel<<<8192, 256, 0, stream>>>(x, mv, Abuf);
        gemm128<0><<<gg1, 256, 0, stream>>>(Abuf, WT + WS, bv, bv, bv, vbuf);
        mix_kernel<<<8192, 256, 0, stream>>>(x, mr, Abuf);
        gemm128<1><<<gg1, 256, 0, stream>>>(Abuf, WT + 2 * WS, br, br, br, rbuf);

        scan_local <<<(M_DIM * NC) / 256, 256, 0, stream>>>(kbuf, vbuf, td, sa, sb, sp);
        scan_prefix<<<M_DIM / 256, 256, 0, stream>>>(td, sa, sb, sp);
        scan_out   <<<(M_DIM * NC) / 256, 256, 0, stream>>>(kbuf, vbuf, rbuf, td, tf,
                                                            sa, sb, sp, rwkv);

        gemm128<2><<<gg1, 256, 0, stream>>>(rwkv, WT + 3 * WS, bo, bo, bo, out);
    }
}